// Round 12
// baseline (99.962 us; speedup 1.0000x reference)
//
#include <hip/hip_runtime.h>

#define NHEADS 8
#define NN     128
#define NCELL  (NN * NN)       // 16384 floats = 64 KiB
#define NT     512             // 8 waves
#define SCALE_F 10.0f

typedef float    nfloat4 __attribute__((ext_vector_type(4)));
typedef _Float16 h4      __attribute__((ext_vector_type(4)));
typedef _Float16 h8      __attribute__((ext_vector_type(8)));

// Blocked FW, B=16, one block (512 thr)/graph. R9 schedule, f16 panels+tile.
// Thread t: rgrp=t>>4 -> rows 4rgrp..+3 ; cgrp=t&15 -> cols 8cgrp..+7 (adjacent).
// dd[4] : 4 rows x 8 cols as packed _Float16 x8 (8 VGPR).
// Per step kb (2 barriers):
//   closure (wave kb, f32 shfl-FW on diag tile) ; bar
//   B' : R_new = D*(f32) (x) R_old(f16) packed   ; bar
//   C  : dd = pk_min(dd, C_old + R_new); extract(kb+1)
//
// LDS: f32 matrix (swizzled) during init/scatter/load; then panels:
//   half-unit offsets:
#define RPAD   136        // R panel stride in halves (+8 pad)
#define RP_O_H 0          // [16][136] R_old  (f16)
#define RP_N_H 2176       // [16][136] R_new  (f16)
#define CP_A_H 4352       // [16][132] C_oldT (f16) parity 0
#define CP_B_H 6464       // parity 1
//   float-unit offsets (above the f16 region):
#define DPS_F  4400       // [16][20] diag tile f32
#define RED_F  4720

__device__ __forceinline__ void extract_panels(const h8 (&dd)[4], float* lds,
                                               _Float16* ldsH, const int kbn,
                                               const int rgrp, const int cgrp,
                                               const int cpH)
{
    if ((rgrp >> 2) == kbn) {                 // wave kbn: row panel
        const int qb = (rgrp & 3) << 2;
        #pragma unroll
        for (int rr = 0; rr < 4; ++rr)
            *reinterpret_cast<h8*>(ldsH + RP_O_H + (qb+rr)*RPAD + (cgrp << 3)) = dd[rr];
        if ((cgrp >> 1) == kbn) {             // diag owners (f32 dump, 2 thr/row-grp)
            const int p = (cgrp & 1) << 3;
            #pragma unroll
            for (int rr = 0; rr < 4; ++rr) {
                *reinterpret_cast<float4*>(&lds[DPS_F + (qb+rr)*20 + p]) =
                    make_float4((float)dd[rr][0], (float)dd[rr][1],
                                (float)dd[rr][2], (float)dd[rr][3]);
                *reinterpret_cast<float4*>(&lds[DPS_F + (qb+rr)*20 + p + 4]) =
                    make_float4((float)dd[rr][4], (float)dd[rr][5],
                                (float)dd[rr][6], (float)dd[rr][7]);
            }
        }
    }
    if ((cgrp >> 1) == kbn) {                 // col panel -> CPT[m][i] (f16)
        const int lcb = (cgrp & 1) << 3;
        #pragma unroll
        for (int e = 0; e < 8; ++e) {
            h4 v = {dd[0][e], dd[1][e], dd[2][e], dd[3][e]};
            *reinterpret_cast<h4*>(ldsH + cpH + (lcb+e)*132 + (rgrp << 2)) = v;
        }
    }
}

// wave kb: f32 in-place shfl closure of the 16x16 diag tile.
__device__ __forceinline__ void closure(float* lds, const int t, const int kb)
{
    if ((t >> 6) == kb) {
        asm volatile("s_waitcnt lgkmcnt(0)" ::: "memory");
        const int l  = t & 63;
        const int i  = l & 15;
        const int jq = l >> 4;
        float4 v = *reinterpret_cast<const float4*>(&lds[DPS_F + i*20 + (jq << 2)]);
        float T0 = v.x, T1 = v.y, T2 = v.z, T3 = v.w;
        #pragma unroll
        for (int k = 0; k < 16; ++k) {
            const int ksrc = ((k >> 2) << 4) | i;
            float dik;
            switch (k & 3) {
                case 0: dik = __shfl(T0, ksrc); break;
                case 1: dik = __shfl(T1, ksrc); break;
                case 2: dik = __shfl(T2, ksrc); break;
                default: dik = __shfl(T3, ksrc); break;
            }
            const int rsrc = (jq << 4) | k;
            const float r0 = __shfl(T0, rsrc);
            const float r1 = __shfl(T1, rsrc);
            const float r2 = __shfl(T2, rsrc);
            const float r3 = __shfl(T3, rsrc);
            T0 = fminf(T0, dik + r0);
            T1 = fminf(T1, dik + r1);
            T2 = fminf(T2, dik + r2);
            T3 = fminf(T3, dik + r3);
        }
        *reinterpret_cast<float4*>(&lds[DPS_F + i*20 + (jq << 2)]) =
            make_float4(T0, T1, T2, T3);
    }
}

// B': R_new[r][j] = min_m D*[r][m] + R_old[m][j]; 256 thr (r=t>>4, 8 cols), packed.
__device__ __forceinline__ void bprime(float* lds, _Float16* ldsH, const int t)
{
    if (t < 256) {
        const int r  = t >> 4;
        const int j8 = t & 15;
        float da[16];
        #pragma unroll
        for (int q = 0; q < 4; ++q) {
            float4 d4 = *reinterpret_cast<const float4*>(&lds[DPS_F + r*20 + (q << 2)]);
            da[4*q+0]=d4.x; da[4*q+1]=d4.y; da[4*q+2]=d4.z; da[4*q+3]=d4.w;
        }
        h8 acc = (h8)(_Float16)__builtin_huge_valf();
        #pragma unroll
        for (int m = 0; m < 16; ++m) {
            h8 rv = *reinterpret_cast<const h8*>(ldsH + RP_O_H + m*RPAD + (j8 << 3));
            h8 d2 = (h8)(_Float16)da[m];
            acc = __builtin_elementwise_min(acc, d2 + rv);
        }
        *reinterpret_cast<h8*>(ldsH + RP_N_H + r*RPAD + (j8 << 3)) = acc;
    }
}

// C: dd = pk_min(dd, C_old[i][m] + R_new[m][j]) over 16 m.
__device__ __forceinline__ void cphase(h8 (&dd)[4], _Float16* ldsH,
                                       const int rgrp, const int cgrp, const int cpH)
{
    #pragma unroll
    for (int m = 0; m < 16; ++m) {
        h4 c4 = *reinterpret_cast<const h4*>(ldsH + cpH + m*132 + (rgrp << 2));
        h8 r8 = *reinterpret_cast<const h8*>(ldsH + RP_N_H + m*RPAD + (cgrp << 3));
        dd[0] = __builtin_elementwise_min(dd[0], (h8)(c4[0]) + r8);
        dd[1] = __builtin_elementwise_min(dd[1], (h8)(c4[1]) + r8);
        dd[2] = __builtin_elementwise_min(dd[2], (h8)(c4[2]) + r8);
        dd[3] = __builtin_elementwise_min(dd[3], (h8)(c4[3]) + r8);
    }
}

__global__ __launch_bounds__(NT, 2)
void spb_fw_kernel(const int* __restrict__ edge_index,
                   const float* __restrict__ edge_weight,
                   const int num_edges, const int epg,
                   float* __restrict__ out)
{
    __shared__ float lds[NCELL];
    _Float16* const ldsH = reinterpret_cast<_Float16*>(lds);
    const float INF = __builtin_huge_valf();
    const int t    = threadIdx.x;
    const int g    = blockIdx.x;
    const int cgrp = t & 15;
    const int rgrp = t >> 4;

    // ---- prefetch edges (4/thread, clamped; dup scatter idempotent) ----
    const int ebase = g * epg;
    int esrc[4], edst[4]; float ew[4];
    #pragma unroll
    for (int k = 0; k < 4; ++k) {
        int e = t + k * NT;
        e = (e < epg) ? e : (epg - 1);
        const int idx = ebase + e;
        esrc[k] = edge_index[idx];
        edst[k] = edge_index[num_edges + idx];
        ew[k]   = edge_weight[idx];
    }

    // ---- init f32 matrix (swizzled: elem(i,col) at i*128 + (col ^ ((i&7)<<2))) ----
    #pragma unroll
    for (int c = 0; c < 8; ++c) {
        const int m   = t + (c << 9);
        const int i   = m >> 5;
        const int scm = m & 31;
        const int c0  = (scm ^ (i & 7)) << 2;
        float4 v;
        v.x = (c0 + 0 == i) ? 0.0f : INF;
        v.y = (c0 + 1 == i) ? 0.0f : INF;
        v.z = (c0 + 2 == i) ? 0.0f : INF;
        v.w = (c0 + 3 == i) ? 0.0f : INF;
        *reinterpret_cast<float4*>(&lds[m << 2]) = v;
    }
    __syncthreads();

    // ---- scatter edges (atomicMin on int view of positive floats) ----
    #pragma unroll
    for (int k = 0; k < 4; ++k) {
        const int u = esrc[k] - g * NN;
        const int v = edst[k] - g * NN;
        if (u != v && (unsigned)u < (unsigned)NN && (unsigned)v < (unsigned)NN) {
            const int a = (u << 7) + (v ^ ((u & 7) << 2));
            atomicMin(reinterpret_cast<int*>(&lds[a]), __float_as_int(ew[k]));
        }
    }
    __syncthreads();

    // ---- load dd (8 adjacent cols/thread), convert to packed f16 ----
    h8 dd[4];
    #pragma unroll
    for (int rr = 0; rr < 4; ++rr) {
        const int i = (rgrp << 2) + rr;
        const int s = i & 7;
        const int q0 = cgrp << 1;
        float4 a = *reinterpret_cast<const float4*>(&lds[(i << 7) + (((q0  ) ^ s) << 2)]);
        float4 b = *reinterpret_cast<const float4*>(&lds[(i << 7) + (((q0+1) ^ s) << 2)]);
        h8 v;
        v[0]=(_Float16)a.x; v[1]=(_Float16)a.y; v[2]=(_Float16)a.z; v[3]=(_Float16)a.w;
        v[4]=(_Float16)b.x; v[5]=(_Float16)b.y; v[6]=(_Float16)b.z; v[7]=(_Float16)b.w;
        dd[rr] = v;
    }
    __syncthreads();   // matrix region dead; panels may be written

    // ---- blocked FW: 8 steps, 2 barriers each (ROLLED) ----
    extract_panels(dd, lds, ldsH, 0, rgrp, cgrp, CP_A_H);
    #pragma unroll 1
    for (int kb = 0; kb < 8; ++kb) {
        closure(lds, t, kb);
        __syncthreads();
        bprime(lds, ldsH, t);
        __syncthreads();
        cphase(dd, ldsH, rgrp, cgrp, (kb & 1) ? CP_B_H : CP_A_H);
        if (kb < 7)
            extract_panels(dd, lds, ldsH, kb + 1, rgrp, cgrp,
                           ((kb + 1) & 1) ? CP_B_H : CP_A_H);
    }
    __syncthreads();

    // ---- reductions (max finite, global max) in f32 ----
    float mF = 0.0f, mA = 0.0f;
    #pragma unroll
    for (int rr = 0; rr < 4; ++rr)
        #pragma unroll
        for (int e = 0; e < 8; ++e) {
            const float f = (float)dd[rr][e];
            mA = fmaxf(mA, f);
            mF = fmaxf(mF, f < INF ? f : 0.0f);
        }
    #pragma unroll
    for (int o = 32; o > 0; o >>= 1) {
        mF = fmaxf(mF, __shfl_xor(mF, o));
        mA = fmaxf(mA, __shfl_xor(mA, o));
    }
    if ((t & 63) == 0) {
        lds[RED_F + ((t >> 6) << 1)]     = mF;
        lds[RED_F + ((t >> 6) << 1) + 1] = mA;
    }
    __syncthreads();
    mF = lds[RED_F]; mA = lds[RED_F + 1];
    #pragma unroll
    for (int wv = 1; wv < 8; ++wv) {
        mF = fmaxf(mF, lds[RED_F + wv*2]);
        mA = fmaxf(mA, lds[RED_F + wv*2 + 1]);
    }
    const float twoF  = 2.0f * mF;
    const float maxv  = fmaxf((mA == INF) ? twoF : mF, 1e-8f);
    const float nscal = -SCALE_F / maxv;

    // ---- normalize, store 8 heads (coalesced, nontemporal) ----
    float* const outg = out + (size_t)g * (NHEADS * NCELL);
    #pragma unroll
    for (int rr = 0; rr < 4; ++rr) {
        const int i = (rgrp << 2) + rr;
        float f[8];
        #pragma unroll
        for (int e = 0; e < 8; ++e) {
            const float x = (float)dd[rr][e];
            f[e] = ((x == INF) ? twoF : x) * nscal;
        }
        nfloat4 va, vb;
        va.x=f[0]; va.y=f[1]; va.z=f[2]; va.w=f[3];
        vb.x=f[4]; vb.y=f[5]; vb.z=f[6]; vb.w=f[7];
        const int o = (i << 7) + (cgrp << 3);
        #pragma unroll
        for (int h = 0; h < NHEADS; ++h) {
            __builtin_nontemporal_store(va, reinterpret_cast<nfloat4*>(&outg[h * NCELL + o]));
            __builtin_nontemporal_store(vb, reinterpret_cast<nfloat4*>(&outg[h * NCELL + o + 4]));
        }
    }
}

extern "C" void kernel_launch(void* const* d_in, const int* in_sizes, int n_in,
                              void* d_out, int out_size, void* d_ws, size_t ws_size,
                              hipStream_t stream)
{
    const int*   edge_index  = (const int*)d_in[0];
    const float* edge_w      = (const float*)d_in[1];
    const int E    = in_sizes[1];
    const int Ntot = in_sizes[2];
    const int G    = Ntot / NN;
    const int epg  = E / G;
    float* out = (float*)d_out;
    spb_fw_kernel<<<G, NT, 0, stream>>>(edge_index, edge_w, E, epg, out);
}

// Round 13
// 96.321 us; speedup vs baseline: 1.0378x; 1.0378x over previous
//
#include <hip/hip_runtime.h>

#define NHEADS 8
#define NN     128
#define NCELL  (NN * NN)       // 16384 floats = 64 KiB
#define NT     512             // 8 waves
#define SCALE_F 10.0f

typedef float    nfloat4 __attribute__((ext_vector_type(4)));
typedef int      nint4   __attribute__((ext_vector_type(4)));
typedef _Float16 h2      __attribute__((ext_vector_type(2)));
typedef _Float16 h4      __attribute__((ext_vector_type(4)));
typedef _Float16 h8      __attribute__((ext_vector_type(8)));

// Blocked FW, B=16, one block (512 thr)/graph, R9 schedule, f16 panels+tile.
// Thread t: rgrp=t>>4 -> rows 4rgrp..+3 ; cgrp=t&15 -> cols 8cgrp..+7 (adjacent).
// dd0..dd3: NAMED h8 (8 cols packed) -- no arrays, no element insertion in hot
// code (R12's scratch-spill lesson); all reshapes via shufflevector.
// Per step kb (2 barriers):
//   closure (wave kb, f32 shfl-FW on diag) ; bar ; B' packed ; bar ;
//   C packed ; extract(kb+1)
//
// LDS: f32 matrix (swizzled) during init/scatter/load; then panels:
//   half-unit offsets:
#define RST    136        // R panel stride in halves (+8 pad)
#define RP_O_H 0          // [16][136] R_old (f16)
#define RP_N_H 2176       // [16][136] R_new (f16)
#define CP_A_H 4352       // [16][132] C_oldT (f16) parity 0
#define CP_B_H 6464       // parity 1
//   float-unit offsets (above the f16 region: 17152B < 17600B):
#define DPS_F  4400       // [16][20] diag tile f32
#define RED_F  4720

// wave kb: f32 in-place shfl closure of the 16x16 diag tile (R9-proven).
__device__ __forceinline__ void closure(float* lds, const int t, const int kb)
{
    if ((t >> 6) == kb) {
        asm volatile("s_waitcnt lgkmcnt(0)" ::: "memory");
        const int l  = t & 63;
        const int i  = l & 15;
        const int jq = l >> 4;
        nfloat4 v = *reinterpret_cast<const nfloat4*>(&lds[DPS_F + i*20 + (jq << 2)]);
        float T0 = v.x, T1 = v.y, T2 = v.z, T3 = v.w;
        #pragma unroll
        for (int k = 0; k < 16; ++k) {
            const int ksrc = ((k >> 2) << 4) | i;
            float dik;
            switch (k & 3) {
                case 0: dik = __shfl(T0, ksrc); break;
                case 1: dik = __shfl(T1, ksrc); break;
                case 2: dik = __shfl(T2, ksrc); break;
                default: dik = __shfl(T3, ksrc); break;
            }
            const int rsrc = (jq << 4) | k;
            const float r0 = __shfl(T0, rsrc);
            const float r1 = __shfl(T1, rsrc);
            const float r2 = __shfl(T2, rsrc);
            const float r3 = __shfl(T3, rsrc);
            T0 = fminf(T0, dik + r0);
            T1 = fminf(T1, dik + r1);
            T2 = fminf(T2, dik + r2);
            T3 = fminf(T3, dik + r3);
        }
        nfloat4 w; w.x = T0; w.y = T1; w.z = T2; w.w = T3;
        *reinterpret_cast<nfloat4*>(&lds[DPS_F + i*20 + (jq << 2)]) = w;
    }
}

__global__ __launch_bounds__(NT, 2)
void spb_fw_kernel(const int* __restrict__ edge_index,
                   const float* __restrict__ edge_weight,
                   const int num_edges, const int epg,
                   float* __restrict__ out)
{
    __shared__ float lds[NCELL];
    _Float16* const ldsH = reinterpret_cast<_Float16*>(lds);
    const float INF = __builtin_huge_valf();
    const int t    = threadIdx.x;
    const int g    = blockIdx.x;
    const int cgrp = t & 15;
    const int rgrp = t >> 4;

    // ---- prefetch edges (4/thread, clamped; dup scatter idempotent) ----
    const int ebase = g * epg;
    int esrc[4], edst[4]; float ew[4];
    #pragma unroll
    for (int k = 0; k < 4; ++k) {
        int e = t + k * NT;
        e = (e < epg) ? e : (epg - 1);
        const int idx = ebase + e;
        esrc[k] = edge_index[idx];
        edst[k] = edge_index[num_edges + idx];
        ew[k]   = edge_weight[idx];
    }

    // ---- init f32 matrix (swizzled: elem(i,col) at i*128 + (col ^ ((i&7)<<2))) ----
    #pragma unroll
    for (int c = 0; c < 8; ++c) {
        const int m   = t + (c << 9);
        const int i   = m >> 5;
        const int scm = m & 31;
        const int c0  = (scm ^ (i & 7)) << 2;
        nfloat4 v;
        v.x = (c0 + 0 == i) ? 0.0f : INF;
        v.y = (c0 + 1 == i) ? 0.0f : INF;
        v.z = (c0 + 2 == i) ? 0.0f : INF;
        v.w = (c0 + 3 == i) ? 0.0f : INF;
        *reinterpret_cast<nfloat4*>(&lds[m << 2]) = v;
    }
    __syncthreads();

    // ---- scatter edges (atomicMin on int view of positive floats) ----
    #pragma unroll
    for (int k = 0; k < 4; ++k) {
        const int u = esrc[k] - g * NN;
        const int v = edst[k] - g * NN;
        if (u != v && (unsigned)u < (unsigned)NN && (unsigned)v < (unsigned)NN) {
            const int a = (u << 7) + (v ^ ((u & 7) << 2));
            atomicMin(reinterpret_cast<int*>(&lds[a]), __float_as_int(ew[k]));
        }
    }
    __syncthreads();

    // ---- load dd (8 adjacent cols/thread), convert to packed f16 ----
    h8 dd0, dd1, dd2, dd3;
#define LOADDD(RR, DD) { \
        const int i_ = (rgrp << 2) + RR; const int s_ = i_ & 7; const int q0_ = cgrp << 1; \
        nfloat4 a_ = *reinterpret_cast<const nfloat4*>(&lds[(i_ << 7) + (((q0_    ) ^ s_) << 2)]); \
        nfloat4 b_ = *reinterpret_cast<const nfloat4*>(&lds[(i_ << 7) + (((q0_ + 1) ^ s_) << 2)]); \
        h4 la_ = __builtin_convertvector(a_, h4); \
        h4 lb_ = __builtin_convertvector(b_, h4); \
        DD = __builtin_shufflevector(la_, lb_, 0, 1, 2, 3, 4, 5, 6, 7); }
    LOADDD(0, dd0) LOADDD(1, dd1) LOADDD(2, dd2) LOADDD(3, dd3)
#undef LOADDD
    __syncthreads();   // matrix region dead; panels may be written

    // ---- extract macro (row panel + diag + col panel for block kbn) ----
#define EXTRACT(KBN, CPH) { \
        const int kbn_ = (KBN); \
        if ((rgrp >> 2) == kbn_) { \
            const int iloc_ = ((rgrp & 3) << 2); \
            *reinterpret_cast<h8*>(ldsH + RP_O_H + (iloc_    ) * RST + (cgrp << 3)) = dd0; \
            *reinterpret_cast<h8*>(ldsH + RP_O_H + (iloc_ + 1) * RST + (cgrp << 3)) = dd1; \
            *reinterpret_cast<h8*>(ldsH + RP_O_H + (iloc_ + 2) * RST + (cgrp << 3)) = dd2; \
            *reinterpret_cast<h8*>(ldsH + RP_O_H + (iloc_ + 3) * RST + (cgrp << 3)) = dd3; \
            if ((cgrp >> 1) == kbn_) { \
                const int p_ = (cgrp & 1) << 3; \
                /* diag rows iloc_..+3, cols p_..p_+7 (f32) */ \
                { h4 lo_ = __builtin_shufflevector(dd0, dd0, 0,1,2,3); \
                  h4 hi_ = __builtin_shufflevector(dd0, dd0, 4,5,6,7); \
                  *reinterpret_cast<nfloat4*>(&lds[DPS_F + (iloc_    )*20 + p_    ]) = __builtin_convertvector(lo_, nfloat4); \
                  *reinterpret_cast<nfloat4*>(&lds[DPS_F + (iloc_    )*20 + p_ + 4]) = __builtin_convertvector(hi_, nfloat4); } \
                { h4 lo_ = __builtin_shufflevector(dd1, dd1, 0,1,2,3); \
                  h4 hi_ = __builtin_shufflevector(dd1, dd1, 4,5,6,7); \
                  *reinterpret_cast<nfloat4*>(&lds[DPS_F + (iloc_ + 1)*20 + p_    ]) = __builtin_convertvector(lo_, nfloat4); \
                  *reinterpret_cast<nfloat4*>(&lds[DPS_F + (iloc_ + 1)*20 + p_ + 4]) = __builtin_convertvector(hi_, nfloat4); } \
                { h4 lo_ = __builtin_shufflevector(dd2, dd2, 0,1,2,3); \
                  h4 hi_ = __builtin_shufflevector(dd2, dd2, 4,5,6,7); \
                  *reinterpret_cast<nfloat4*>(&lds[DPS_F + (iloc_ + 2)*20 + p_    ]) = __builtin_convertvector(lo_, nfloat4); \
                  *reinterpret_cast<nfloat4*>(&lds[DPS_F + (iloc_ + 2)*20 + p_ + 4]) = __builtin_convertvector(hi_, nfloat4); } \
                { h4 lo_ = __builtin_shufflevector(dd3, dd3, 0,1,2,3); \
                  h4 hi_ = __builtin_shufflevector(dd3, dd3, 4,5,6,7); \
                  *reinterpret_cast<nfloat4*>(&lds[DPS_F + (iloc_ + 3)*20 + p_    ]) = __builtin_convertvector(lo_, nfloat4); \
                  *reinterpret_cast<nfloat4*>(&lds[DPS_F + (iloc_ + 3)*20 + p_ + 4]) = __builtin_convertvector(hi_, nfloat4); } \
            } \
        } \
        if ((cgrp >> 1) == kbn_) { \
            const int lcb_ = (cgrp & 1) << 3; \
            _Float16* cp_ = ldsH + (CPH) + (rgrp << 2); \
            /* CPT[m][i]: column e of this thread's 8 cols, rows 4rgrp..+3 */ \
            CPW_(0) CPW_(1) CPW_(2) CPW_(3) CPW_(4) CPW_(5) CPW_(6) CPW_(7) \
        } }
#define CPW_(E) { h2 a01_ = __builtin_shufflevector(dd0, dd1, E, 8 + E); \
                  h2 a23_ = __builtin_shufflevector(dd2, dd3, E, 8 + E); \
                  h4 v_   = __builtin_shufflevector(a01_, a23_, 0, 1, 2, 3); \
                  *reinterpret_cast<h4*>(cp_ + (lcb_ + E) * 132) = v_; }

    // ---- blocked FW: 8 steps, 2 barriers each (ROLLED) ----
    EXTRACT(0, CP_A_H)
    #pragma unroll 1
    for (int kb = 0; kb < 8; ++kb) {
        closure(lds, t, kb);
        __syncthreads();
        // B': R_new = D*(f32) (x) R_old(f16); 256 thr, 1 row x 8 cols
        if (t < 256) {
            const int r  = t >> 4;
            const int j8 = t & 15;
            nfloat4 d0 = *reinterpret_cast<const nfloat4*>(&lds[DPS_F + r*20 + 0]);
            nfloat4 d1 = *reinterpret_cast<const nfloat4*>(&lds[DPS_F + r*20 + 4]);
            nfloat4 d2 = *reinterpret_cast<const nfloat4*>(&lds[DPS_F + r*20 + 8]);
            nfloat4 d3 = *reinterpret_cast<const nfloat4*>(&lds[DPS_F + r*20 + 12]);
            h8 acc = (h8)(_Float16)INF;
#define BPM_(DQ, MM, CMP) { h8 rv_ = *reinterpret_cast<const h8*>(ldsH + RP_O_H + (MM) * RST + (j8 << 3)); \
                            acc = __builtin_elementwise_min(acc, ((h8)(_Float16)(DQ.CMP)) + rv_); }
            BPM_(d0, 0, x) BPM_(d0, 1, y) BPM_(d0, 2, z) BPM_(d0, 3, w)
            BPM_(d1, 4, x) BPM_(d1, 5, y) BPM_(d1, 6, z) BPM_(d1, 7, w)
            BPM_(d2, 8, x) BPM_(d2, 9, y) BPM_(d2,10, z) BPM_(d2,11, w)
            BPM_(d3,12, x) BPM_(d3,13, y) BPM_(d3,14, z) BPM_(d3,15, w)
#undef BPM_
            *reinterpret_cast<h8*>(ldsH + RP_N_H + r * RST + (j8 << 3)) = acc;
        }
        __syncthreads();
        // C: dd = pk_min(dd, C_old[i][m] + R_new[m][j]) over 16 m
        {
            const int cpH = (kb & 1) ? CP_B_H : CP_A_H;
            _Float16* const cpp = ldsH + cpH + (rgrp << 2);
            _Float16* const rpp = ldsH + RP_N_H + (cgrp << 3);
            #pragma unroll
            for (int m = 0; m < 16; ++m) {
                h4 c4 = *reinterpret_cast<const h4*>(cpp + m * 132);
                h8 r8 = *reinterpret_cast<const h8*>(rpp + m * RST);
                const _Float16 c0 = c4[0], c1 = c4[1], c2 = c4[2], c3 = c4[3];
                dd0 = __builtin_elementwise_min(dd0, ((h8)c0) + r8);
                dd1 = __builtin_elementwise_min(dd1, ((h8)c1) + r8);
                dd2 = __builtin_elementwise_min(dd2, ((h8)c2) + r8);
                dd3 = __builtin_elementwise_min(dd3, ((h8)c3) + r8);
            }
        }
        if (kb < 7) {
            if ((kb + 1) & 1) { EXTRACT(kb + 1, CP_B_H) }
            else              { EXTRACT(kb + 1, CP_A_H) }
        }
    }
#undef CPW_
#undef EXTRACT
    __syncthreads();

    // ---- reductions (max finite, global max) in f32 ----
    float mF = 0.0f, mA = 0.0f;
#define REDROW(DD) { \
        h4 lo_ = __builtin_shufflevector(DD, DD, 0,1,2,3); \
        h4 hi_ = __builtin_shufflevector(DD, DD, 4,5,6,7); \
        nfloat4 fa_ = __builtin_convertvector(lo_, nfloat4); \
        nfloat4 fb_ = __builtin_convertvector(hi_, nfloat4); \
        mA = fmaxf(mA, fmaxf(fmaxf(fa_.x, fa_.y), fmaxf(fa_.z, fa_.w))); \
        mA = fmaxf(mA, fmaxf(fmaxf(fb_.x, fb_.y), fmaxf(fb_.z, fb_.w))); \
        mF = fmaxf(mF, fmaxf(fmaxf(fa_.x < INF ? fa_.x : 0.0f, fa_.y < INF ? fa_.y : 0.0f), \
                             fmaxf(fa_.z < INF ? fa_.z : 0.0f, fa_.w < INF ? fa_.w : 0.0f))); \
        mF = fmaxf(mF, fmaxf(fmaxf(fb_.x < INF ? fb_.x : 0.0f, fb_.y < INF ? fb_.y : 0.0f), \
                             fmaxf(fb_.z < INF ? fb_.z : 0.0f, fb_.w < INF ? fb_.w : 0.0f))); }
    REDROW(dd0) REDROW(dd1) REDROW(dd2) REDROW(dd3)
#undef REDROW
    #pragma unroll
    for (int o = 32; o > 0; o >>= 1) {
        mF = fmaxf(mF, __shfl_xor(mF, o));
        mA = fmaxf(mA, __shfl_xor(mA, o));
    }
    if ((t & 63) == 0) {
        lds[RED_F + ((t >> 6) << 1)]     = mF;
        lds[RED_F + ((t >> 6) << 1) + 1] = mA;
    }
    __syncthreads();
    mF = lds[RED_F]; mA = lds[RED_F + 1];
    #pragma unroll
    for (int wv = 1; wv < 8; ++wv) {
        mF = fmaxf(mF, lds[RED_F + wv*2]);
        mA = fmaxf(mA, lds[RED_F + wv*2 + 1]);
    }
    const float twoF  = 2.0f * mF;
    const float maxv  = fmaxf((mA == INF) ? twoF : mF, 1e-8f);
    const float nscal = -SCALE_F / maxv;

    // ---- normalize (bit-select INF -> twoF), store 8 heads nontemporal ----
    float* const outg = out + (size_t)g * (NHEADS * NCELL);
    const nint4 infb = (nint4)0x7f800000;
    nfloat4 two4; two4.x = twoF; two4.y = twoF; two4.z = twoF; two4.w = twoF;
    const nint4 twob = __builtin_bit_cast(nint4, two4);
#define STROW(RR, DD) { \
        const int i_ = (rgrp << 2) + RR; \
        h4 lo_ = __builtin_shufflevector(DD, DD, 0,1,2,3); \
        h4 hi_ = __builtin_shufflevector(DD, DD, 4,5,6,7); \
        nfloat4 fa_ = __builtin_convertvector(lo_, nfloat4); \
        nfloat4 fb_ = __builtin_convertvector(hi_, nfloat4); \
        nint4 ba_ = __builtin_bit_cast(nint4, fa_); \
        nint4 bb_ = __builtin_bit_cast(nint4, fb_); \
        nint4 ma_ = (ba_ == infb); \
        nint4 mb_ = (bb_ == infb); \
        nfloat4 va_ = __builtin_bit_cast(nfloat4, (ma_ & twob) | (~ma_ & ba_)) * nscal; \
        nfloat4 vb_ = __builtin_bit_cast(nfloat4, (mb_ & twob) | (~mb_ & bb_)) * nscal; \
        const int o_ = (i_ << 7) + (cgrp << 3); \
        _Pragma("unroll") \
        for (int h = 0; h < NHEADS; ++h) { \
            __builtin_nontemporal_store(va_, reinterpret_cast<nfloat4*>(&outg[h * NCELL + o_])); \
            __builtin_nontemporal_store(vb_, reinterpret_cast<nfloat4*>(&outg[h * NCELL + o_ + 4])); \
        } }
    STROW(0, dd0) STROW(1, dd1) STROW(2, dd2) STROW(3, dd3)
#undef STROW
}

extern "C" void kernel_launch(void* const* d_in, const int* in_sizes, int n_in,
                              void* d_out, int out_size, void* d_ws, size_t ws_size,
                              hipStream_t stream)
{
    const int*   edge_index  = (const int*)d_in[0];
    const float* edge_w      = (const float*)d_in[1];
    const int E    = in_sizes[1];
    const int Ntot = in_sizes[2];
    const int G    = Ntot / NN;
    const int epg  = E / G;
    float* out = (float*)d_out;
    spb_fw_kernel<<<G, NT, 0, stream>>>(edge_index, edge_w, E, epg, out);
}

// Round 14
// 61.338 us; speedup vs baseline: 1.6297x; 1.5703x over previous
//
#include <hip/hip_runtime.h>

#define NHEADS 8
#define NN     128
#define NCELL  (NN * NN)       // 16384 floats = 64 KiB
#define NT     512             // 8 waves
#define SCALE_F 10.0f

typedef float nfloat4 __attribute__((ext_vector_type(4)));

// Blocked FW, B=16, one block (512 thr)/graph, f32 (R9 trunk).
// Thread t: rgrp=t>>4 -> rows 4rgrp..+3 ; cgrp=t&15 -> cols 4cgrp+64c (c=0,1).
// dd[4][8] register-resident.
// Step kb (2 barriers):  B'(kb) ; bar ; C(kb) + extract(kb+1) + closure(kb+1)
//                        [closure runs in C's shadow: wave kb+1 only, intra-wave
//                         after its own diag extract] ; bar
// Prologue: extract(0) + closure(0) (wave 0, intra-wave) ; bar.
//
// LDS float offsets:
#define RP_O 0        // [16][128] R_old
#define RP_N 2048     // [16][128] R_new
#define CP_As 4096    // [16][132] C_oldT parity 0
#define CP_Bs 6208    // parity 1
#define DPS  8320     // [16][20] diag tile / D*
#define RED  8640

template<int CBN>   // CBN = 4*(kbn>>2): dd column-half holding block kbn's cols
__device__ __forceinline__ void extract_panels(const float (&dd)[4][8], float* lds,
                                               const int kbn, const int t,
                                               const int rgrp, const int cgrp,
                                               const int cpbase)
{
    if ((rgrp >> 2) == kbn) {                 // wave kbn: row panel + diag
        const int q = rgrp & 3;
        #pragma unroll
        for (int rr = 0; rr < 4; ++rr) {
            const int iloc = 4 * q + rr;
            #pragma unroll
            for (int c = 0; c < 2; ++c) {
                *reinterpret_cast<float4*>(
                    &lds[RP_O + iloc * 128 + (cgrp << 2) + (c << 6)]) =
                    make_float4(dd[rr][c*4+0], dd[rr][c*4+1],
                                dd[rr][c*4+2], dd[rr][c*4+3]);
            }
        }
        const int p = cgrp - 4 * (kbn & 3);
        if ((unsigned)p < 4u) {
            #pragma unroll
            for (int rr = 0; rr < 4; ++rr) {
                *reinterpret_cast<float4*>(&lds[DPS + (4*q+rr) * 20 + (p << 2)]) =
                    make_float4(dd[rr][CBN+0], dd[rr][CBN+1],
                                dd[rr][CBN+2], dd[rr][CBN+3]);
            }
        }
    }
    {
        const int q2 = cgrp - 4 * (kbn & 3);   // col panel -> CPT[m][i]
        if ((unsigned)q2 < 4u) {
            #pragma unroll
            for (int e = 0; e < 4; ++e) {
                const int m = 4 * q2 + e;
                *reinterpret_cast<float4*>(&lds[cpbase + m * 132 + (rgrp << 2)]) =
                    make_float4(dd[0][CBN+e], dd[1][CBN+e],
                                dd[2][CBN+e], dd[3][CBN+e]);
            }
        }
    }
}

// wave kbn: f32 in-place shfl closure of DPS (runs in C's shadow; the
// diag writes it consumes are its own wave's -> lgkmcnt(0) suffices).
__device__ __forceinline__ void closure(float* lds, const int t, const int kbn)
{
    if ((t >> 6) == kbn) {
        asm volatile("s_waitcnt lgkmcnt(0)" ::: "memory");
        const int l  = t & 63;
        const int i  = l & 15;
        const int jq = l >> 4;
        float4 v = *reinterpret_cast<const float4*>(&lds[DPS + i*20 + (jq << 2)]);
        float T0 = v.x, T1 = v.y, T2 = v.z, T3 = v.w;
        #pragma unroll
        for (int k = 0; k < 16; ++k) {
            const int ksrc = ((k >> 2) << 4) | i;
            float dik;
            switch (k & 3) {
                case 0: dik = __shfl(T0, ksrc); break;
                case 1: dik = __shfl(T1, ksrc); break;
                case 2: dik = __shfl(T2, ksrc); break;
                default: dik = __shfl(T3, ksrc); break;
            }
            const int rsrc = (jq << 4) | k;
            const float r0 = __shfl(T0, rsrc);
            const float r1 = __shfl(T1, rsrc);
            const float r2 = __shfl(T2, rsrc);
            const float r3 = __shfl(T3, rsrc);
            T0 = fminf(T0, dik + r0);
            T1 = fminf(T1, dik + r1);
            T2 = fminf(T2, dik + r2);
            T3 = fminf(T3, dik + r3);
        }
        *reinterpret_cast<float4*>(&lds[DPS + i*20 + (jq << 2)]) =
            make_float4(T0, T1, T2, T3);
    }
}

// B': R_new[r][j] = min_m D*[r][m] + R_old[m][j]; ALL 512 threads:
// r = t>>5 (0..15), 4 cols at 4*(t&31). D* row r broadcast within half-wave.
__device__ __forceinline__ void bprime(float* lds, const int t)
{
    const float INF = __builtin_huge_valf();
    const int r  = t >> 5;
    const int j4 = (t & 31) << 2;
    float da[16];
    #pragma unroll
    for (int q = 0; q < 4; ++q) {
        float4 d4 = *reinterpret_cast<const float4*>(&lds[DPS + r*20 + (q << 2)]);
        da[4*q+0]=d4.x; da[4*q+1]=d4.y; da[4*q+2]=d4.z; da[4*q+3]=d4.w;
    }
    float a0 = INF, a1 = INF, a2 = INF, a3 = INF;
    #pragma unroll
    for (int m = 0; m < 16; ++m) {
        float4 rv = *reinterpret_cast<const float4*>(&lds[RP_O + m*128 + j4]);
        a0 = fminf(a0, da[m] + rv.x);
        a1 = fminf(a1, da[m] + rv.y);
        a2 = fminf(a2, da[m] + rv.z);
        a3 = fminf(a3, da[m] + rv.w);
    }
    *reinterpret_cast<float4*>(&lds[RP_N + r*128 + j4]) =
        make_float4(a0, a1, a2, a3);
}

// C: dd = min(dd, C_old[i][m] + R_new[m][j]) over 16 m (R9-proven).
__device__ __forceinline__ void cphase(float (&dd)[4][8], float* lds,
                                       const int rgrp, const int cgrp,
                                       const int cpbase)
{
    #pragma unroll
    for (int mq = 0; mq < 4; ++mq) {
        float4 cp[4], ra[4], rb[4];
        #pragma unroll
        for (int e = 0; e < 4; ++e) {
            const int m = 4*mq + e;
            cp[e] = *reinterpret_cast<const float4*>(&lds[cpbase + m*132 + (rgrp<<2)]);
            ra[e] = *reinterpret_cast<const float4*>(&lds[RP_N + m*128 + (cgrp<<2)]);
            rb[e] = *reinterpret_cast<const float4*>(&lds[RP_N + m*128 + (cgrp<<2) + 64]);
        }
        #pragma unroll
        for (int e2 = 0; e2 < 2; ++e2) {
            const float c0[4]  = {cp[2*e2].x, cp[2*e2].y, cp[2*e2].z, cp[2*e2].w};
            const float c1[4]  = {cp[2*e2+1].x, cp[2*e2+1].y, cp[2*e2+1].z, cp[2*e2+1].w};
            const float ra0[4] = {ra[2*e2].x, ra[2*e2].y, ra[2*e2].z, ra[2*e2].w};
            const float ra1[4] = {ra[2*e2+1].x, ra[2*e2+1].y, ra[2*e2+1].z, ra[2*e2+1].w};
            const float rb0[4] = {rb[2*e2].x, rb[2*e2].y, rb[2*e2].z, rb[2*e2].w};
            const float rb1[4] = {rb[2*e2+1].x, rb[2*e2+1].y, rb[2*e2+1].z, rb[2*e2+1].w};
            #pragma unroll
            for (int rr = 0; rr < 4; ++rr) {
                #pragma unroll
                for (int e = 0; e < 4; ++e) {
                    dd[rr][e]   = fminf(fminf(dd[rr][e],   c0[rr] + ra0[e]), c1[rr] + ra1[e]);
                    dd[rr][4+e] = fminf(fminf(dd[rr][4+e], c0[rr] + rb0[e]), c1[rr] + rb1[e]);
                }
            }
        }
    }
}

__global__ __launch_bounds__(NT, 2)
void spb_fw_kernel(const int* __restrict__ edge_index,
                   const float* __restrict__ edge_weight,
                   const int num_edges, const int epg,
                   float* __restrict__ out)
{
    __shared__ float lds[NCELL];
    const float INF = __builtin_huge_valf();
    const int t    = threadIdx.x;
    const int g    = blockIdx.x;
    const int cgrp = t & 15;
    const int rgrp = t >> 4;

    // ---- prefetch edges (4/thread, clamped; dup scatter idempotent) ----
    const int ebase = g * epg;
    int esrc[4], edst[4]; float ew[4];
    #pragma unroll
    for (int k = 0; k < 4; ++k) {
        int e = t + k * NT;
        e = (e < epg) ? e : (epg - 1);
        const int idx = ebase + e;
        esrc[k] = edge_index[idx];
        edst[k] = edge_index[num_edges + idx];
        ew[k]   = edge_weight[idx];
    }

    // ---- init matrix (swizzled: elem(i,col) at i*128 + (col ^ ((i&7)<<2))) ----
    #pragma unroll
    for (int c = 0; c < 8; ++c) {
        const int m   = t + (c << 9);
        const int i   = m >> 5;
        const int scm = m & 31;
        const int c0  = (scm ^ (i & 7)) << 2;
        float4 v;
        v.x = (c0 + 0 == i) ? 0.0f : INF;
        v.y = (c0 + 1 == i) ? 0.0f : INF;
        v.z = (c0 + 2 == i) ? 0.0f : INF;
        v.w = (c0 + 3 == i) ? 0.0f : INF;
        *reinterpret_cast<float4*>(&lds[m << 2]) = v;
    }
    __syncthreads();

    // ---- scatter edges (atomicMin on int view of positive floats) ----
    #pragma unroll
    for (int k = 0; k < 4; ++k) {
        const int u = esrc[k] - g * NN;
        const int v = edst[k] - g * NN;
        if (u != v && (unsigned)u < (unsigned)NN && (unsigned)v < (unsigned)NN) {
            const int a = (u << 7) + (v ^ ((u & 7) << 2));
            atomicMin(reinterpret_cast<int*>(&lds[a]), __float_as_int(ew[k]));
        }
    }
    __syncthreads();

    // ---- load dd: dd[rr][c*4+e] = d[4rgrp+rr][4cgrp+64c+e] ----
    float dd[4][8];
    #pragma unroll
    for (int rr = 0; rr < 4; ++rr) {
        const int i = (rgrp << 2) + rr;
        const int s = i & 7;
        #pragma unroll
        for (int c = 0; c < 2; ++c) {
            float4 v = *reinterpret_cast<const float4*>(
                &lds[(i << 7) + (((cgrp + 16*c) ^ s) << 2)]);
            dd[rr][c*4+0]=v.x; dd[rr][c*4+1]=v.y; dd[rr][c*4+2]=v.z; dd[rr][c*4+3]=v.w;
        }
    }
    __syncthreads();   // matrix region dead; panels may be written

    // ---- prologue: extract(0) + closure(0) in wave 0's shadow ----
    extract_panels<0>(dd, lds, 0, t, rgrp, cgrp, CP_As);
    closure(lds, t, 0);
    __syncthreads();

    // ---- blocked FW: 8 steps, 2 barriers each (ROLLED) ----
    #pragma unroll 1
    for (int kb = 0; kb < 8; ++kb) {
        bprime(lds, t);
        __syncthreads();
        cphase(dd, lds, rgrp, cgrp, (kb & 1) ? CP_Bs : CP_As);
        if (kb < 7) {
            const int kbn = kb + 1;
            const int cpb = (kbn & 1) ? CP_Bs : CP_As;
            if (kbn < 4) extract_panels<0>(dd, lds, kbn, t, rgrp, cgrp, cpb);
            else         extract_panels<4>(dd, lds, kbn, t, rgrp, cgrp, cpb);
            closure(lds, t, kbn);    // wave kbn only, intra-wave, in C's shadow
        }
        __syncthreads();
    }

    // ---- reductions (max finite, global max) ----
    float mF = 0.0f, mA = 0.0f;
    #pragma unroll
    for (int rr = 0; rr < 4; ++rr)
        #pragma unroll
        for (int j = 0; j < 8; ++j) {
            const float v = dd[rr][j];
            mA = fmaxf(mA, v);
            mF = fmaxf(mF, v < INF ? v : 0.0f);
        }
    #pragma unroll
    for (int o = 32; o > 0; o >>= 1) {
        mF = fmaxf(mF, __shfl_xor(mF, o));
        mA = fmaxf(mA, __shfl_xor(mA, o));
    }
    if ((t & 63) == 0) {
        lds[RED + ((t >> 6) << 1)]     = mF;
        lds[RED + ((t >> 6) << 1) + 1] = mA;
    }
    __syncthreads();
    mF = lds[RED]; mA = lds[RED + 1];
    #pragma unroll
    for (int wv = 1; wv < 8; ++wv) {
        mF = fmaxf(mF, lds[RED + wv*2]);
        mA = fmaxf(mA, lds[RED + wv*2 + 1]);
    }
    const float twoF  = 2.0f * mF;
    const float maxv  = fmaxf((mA == INF) ? twoF : mF, 1e-8f);
    const float nscal = -SCALE_F / maxv;

    // ---- normalize in registers, store 8 heads (coalesced, nontemporal) ----
    float* const outg = out + (size_t)g * (NHEADS * NCELL);
    #pragma unroll
    for (int rr = 0; rr < 4; ++rr) {
        const int i = (rgrp << 2) + rr;
        #pragma unroll
        for (int c = 0; c < 2; ++c) {
            nfloat4 v;
            v.x = ((dd[rr][c*4+0] == INF) ? twoF : dd[rr][c*4+0]) * nscal;
            v.y = ((dd[rr][c*4+1] == INF) ? twoF : dd[rr][c*4+1]) * nscal;
            v.z = ((dd[rr][c*4+2] == INF) ? twoF : dd[rr][c*4+2]) * nscal;
            v.w = ((dd[rr][c*4+3] == INF) ? twoF : dd[rr][c*4+3]) * nscal;
            const int o = (i << 7) + (cgrp << 2) + (c << 6);
            #pragma unroll
            for (int h = 0; h < NHEADS; ++h) {
                __builtin_nontemporal_store(
                    v, reinterpret_cast<nfloat4*>(&outg[h * NCELL + o]));
            }
        }
    }
}

extern "C" void kernel_launch(void* const* d_in, const int* in_sizes, int n_in,
                              void* d_out, int out_size, void* d_ws, size_t ws_size,
                              hipStream_t stream)
{
    const int*   edge_index  = (const int*)d_in[0];
    const float* edge_w      = (const float*)d_in[1];
    const int E    = in_sizes[1];
    const int Ntot = in_sizes[2];
    const int G    = Ntot / NN;
    const int epg  = E / G;
    float* out = (float*)d_out;
    spb_fw_kernel<<<G, NT, 0, stream>>>(edge_index, edge_w, E, epg, out);
}